// Round 3
// baseline (832.319 us; speedup 1.0000x reference)
//
#include <hip/hip_runtime.h>
#include <cstdint>

#define NH 16
#define HD 128
#define NTBL 96
#define PT_OFF 32            // prompt blocks skipped: 512/16
#define NSPLIT 16
#define SPLIT_BLOCKS 4       // 64 positions per split
#define QK_SCALE 0.08838834764831845f
#define NEG_INF -1e30f
#define NB 16                // batch

// Fused flash-decode: split WGs compute partial (O,m,l) over cached positions
// [0, ctx-1); the last-arriving WG per (b,h) (device-scope atomic counter)
// merges all partials + the new token (k_new/v_new at pos ctx-1) and writes out.
// Caches are never written (reference's scatter only matters through out).
__global__ __launch_bounds__(256) void attn_fused_kernel(
    const float* __restrict__ q,
    const float* __restrict__ key_cache,
    const float* __restrict__ value_cache,
    const float* __restrict__ k_new,
    const float* __restrict__ v_new,
    const int* __restrict__ block_tables,
    const int* __restrict__ context_lens,
    const float* __restrict__ attn_bias,
    float* __restrict__ ws,
    unsigned* __restrict__ cnt,
    float* __restrict__ out)
{
    const int s = blockIdx.x, h = blockIdx.y, b = blockIdx.z;
    const int ctx = context_lens[b];
    const int cap = ctx - 1;                 // cached positions: [0, cap)
    const int nbc = (ctx + 14) >> 4;         // ceil(cap/16) cached blocks
    const int nsv = (nbc + SPLIT_BLOCKS - 1) >> 2;
    const int nact = (nsv > 0) ? nsv : 1;    // split 0 always participates
    if (s >= nact) return;
    const int jb0 = s * SPLIT_BLOCKS;
    const int nbl = min(SPLIT_BLOCKS, nbc - jb0);   // 0 only when s==0 && nbc==0

    __shared__ float sc[64];                 // raw dots
    __shared__ float sp[64];                 // probs
    __shared__ int   sbt[SPLIT_BLOCKS];
    __shared__ float outA[128], outB[128];
    __shared__ float s2[2];
    __shared__ int   lastFlag;

    const int tid = threadIdx.x;
    const int wave = tid >> 6, lane = tid & 63;
    const int half = lane >> 5, lq = lane & 31;

    if (tid < SPLIT_BLOCKS) sbt[tid] = block_tables[b*NTBL + PT_OFF + jb0 + tid];
    // Per-lane query fragment: dims [lq*4, lq*4+4)
    const float4 qv = *(const float4*)(q + (size_t)b*2048 + h*HD + lq*4);
    __syncthreads();

    // ---- hoisted V loads: thread (team,d) owns 64B d-rows of blocks team, team+2.
    const int team = tid >> 7, d = tid & 127;
    float4 va0, va1, va2, va3, vb0, vb1, vb2, vb3;
    va0 = va1 = va2 = va3 = make_float4(0.f, 0.f, 0.f, 0.f);
    vb0 = vb1 = vb2 = vb3 = make_float4(0.f, 0.f, 0.f, 0.f);
    if (team < nbl) {
        const float4* vp = (const float4*)(value_cache + ((size_t)sbt[team]*NH + h)*2048) + d*4;
        va0 = vp[0]; va1 = vp[1]; va2 = vp[2]; va3 = vp[3];
    }
    if (team + 2 < nbl) {
        const float4* vp = (const float4*)(value_cache + ((size_t)sbt[team+2]*NH + h)*2048) + d*4;
        vb0 = vp[0]; vb1 = vp[1]; vb2 = vp[2]; vb3 = vp[3];
    }

    // ---- QK: one wave streams one 8KB key block with coalesced float4s.
    if (wave < nbl) {
        const int blk = sbt[wave];
        const float4* kb = (const float4*)(key_cache + ((size_t)blk*NH + h)*2048);
        #pragma unroll
        for (int i = 0; i < 8; ++i) {
            const float4 kv = kb[i*64 + lane];
            float part = kv.x*qv.x + kv.y*qv.y + kv.z*qv.z + kv.w*qv.w;
            part += __shfl_xor(part, 1);
            part += __shfl_xor(part, 2);
            part += __shfl_xor(part, 4);
            part += __shfl_xor(part, 8);
            part += __shfl_xor(part, 16);   // 32-lane half holds full 128-dim dot
            if (lq == 0) sc[wave*16 + i*2 + half] = part;
        }
    }
    __syncthreads();

    // ---- softmax over <=64 positions (redundant per wave; lane==pos)
    const int gpos = jb0*16 + lane;
    const bool valid = gpos < cap;           // also masks pos >= nbl*16
    const float x = valid
        ? (sc[lane]*QK_SCALE + attn_bias[((size_t)b*NH + h)*1024 + gpos])
        : NEG_INF;
    float m = x;
    #pragma unroll
    for (int msk = 32; msk >= 1; msk >>= 1) m = fmaxf(m, __shfl_xor(m, msk));
    const float pexp = valid ? __expf(x - m) : 0.0f;
    float l = pexp;
    #pragma unroll
    for (int msk = 32; msk >= 1; msk >>= 1) l += __shfl_xor(l, msk);
    if (wave == 0) sp[lane] = pexp;
    __syncthreads();

    // ---- PV from registers; probs broadcast from LDS (wave-uniform addrs)
    float acc = 0.0f;
    {
        const float* pr = sp + team*16;
        acc += pr[0]*va0.x + pr[1]*va0.y + pr[2]*va0.z  + pr[3]*va0.w;
        acc += pr[4]*va1.x + pr[5]*va1.y + pr[6]*va1.z  + pr[7]*va1.w;
        acc += pr[8]*va2.x + pr[9]*va2.y + pr[10]*va2.z + pr[11]*va2.w;
        acc += pr[12]*va3.x + pr[13]*va3.y + pr[14]*va3.z + pr[15]*va3.w;
    }
    {
        const float* pr = sp + (team+2)*16;
        acc += pr[0]*vb0.x + pr[1]*vb0.y + pr[2]*vb0.z  + pr[3]*vb0.w;
        acc += pr[4]*vb1.x + pr[5]*vb1.y + pr[6]*vb1.z  + pr[7]*vb1.w;
        acc += pr[8]*vb2.x + pr[9]*vb2.y + pr[10]*vb2.z + pr[11]*vb2.w;
        acc += pr[12]*vb3.x + pr[13]*vb3.y + pr[14]*vb3.z + pr[15]*vb3.w;
    }
    if (team == 0) outA[d] = acc; else outB[d] = acc;
    __syncthreads();

    // ---- write partial (O, m, l)
    float* wsp = ws + (((size_t)b*NH + h)*NSPLIT + s)*130;
    if (tid < 128) wsp[tid] = outA[tid] + outB[tid];
    if (tid == 0) { wsp[128] = m; wsp[129] = l; }
    __syncthreads();                         // drain all WG stores (vmcnt(0) before barrier)

    // ---- last-WG-merges (device-scope atomic + fences)
    if (tid == 0) {
        __threadfence();
        unsigned old = __hip_atomic_fetch_add(cnt + b*NH + h, 1u,
                                              __ATOMIC_ACQ_REL, __HIP_MEMORY_SCOPE_AGENT);
        lastFlag = (old == (unsigned)(nact - 1)) ? 1 : 0;
    }
    __syncthreads();
    if (lastFlag) {
        __threadfence();                     // acquire: see other splits' partials
        const size_t qoff = (size_t)b*2048 + h*HD + d;
        // new-token score: q . k_new over 128 dims (threads 0..127)
        float p = (tid < 128) ? q[qoff] * k_new[qoff] : 0.0f;
        #pragma unroll
        for (int msk = 32; msk >= 1; msk >>= 1) p += __shfl_xor(p, msk);
        if (lane == 0 && wave < 2) s2[wave] = p;
        __syncthreads();
        if (tid < 128) {
            const float score_new = (s2[0] + s2[1]) * QK_SCALE
                                  + attn_bias[((size_t)b*NH + h)*1024 + cap];
            const float* base = ws + ((size_t)b*NH + h)*NSPLIT*130;
            float M = score_new;
            for (int ss = 0; ss < nact; ++ss) M = fmaxf(M, base[ss*130 + 128]);
            const float w = __expf(score_new - M);
            float L = w, acc2 = w * v_new[qoff];
            for (int ss = 0; ss < nact; ++ss) {
                const float e = __expf(base[ss*130 + 128] - M);
                L    += base[ss*130 + 129] * e;
                acc2 += base[ss*130 + d] * e;
            }
            out[qoff] = acc2 / L;
        }
    }
}

extern "C" void kernel_launch(void* const* d_in, const int* in_sizes, int n_in,
                              void* d_out, int out_size, void* d_ws, size_t ws_size,
                              hipStream_t stream) {
    (void)in_sizes; (void)n_in; (void)out_size; (void)ws_size;
    const float* q        = (const float*)d_in[0];
    const float* k_new    = (const float*)d_in[1];
    const float* v_new    = (const float*)d_in[2];
    const float* kcache   = (const float*)d_in[3];
    const float* vcache   = (const float*)d_in[4];
    const int* btables    = (const int*)d_in[6];
    const int* ctx_lens   = (const int*)d_in[7];
    const float* bias     = (const float*)d_in[8];
    float* ws  = (float*)d_ws;                       // partials: 16*16*16*130 floats
    unsigned* cnt = (unsigned*)(ws + (size_t)NB*NH*NSPLIT*130);   // +1KB counters
    float* out = (float*)d_out;

    hipMemsetAsync(cnt, 0, NB*NH*sizeof(unsigned), stream);       // graph-safe memset node
    attn_fused_kernel<<<dim3(NSPLIT, NH, NB), 256, 0, stream>>>(
        q, kcache, vcache, k_new, v_new, btables, ctx_lens, bias, ws, cnt, out);
}